// Round 6
// baseline (415.873 us; speedup 1.0000x reference)
//
#include <hip/hip_runtime.h>

#define NUM_EMB 1024
#define EMB_DIM 64
#define NPIX    131072                 // 32*64*64 pixels
#define ZQ_ELEMS 8388608               // NPIX * EMB_DIM

// d_out is FLOAT32: [ z_q (8388608, b-c-h-w) | loss (1) | enc (131072) ]

__global__ void vq_zero(float* __restrict__ loss_out) { loss_out[0] = 0.f; }

// numpy pairwise-sum (n=64, scalar 8-accumulator path) of x[j]*x[j].
// Token-identical to the round-5 passing version.
__device__ __forceinline__ float np_sumsq64(const float* __restrict__ x) {
    float q[EMB_DIM];
    #pragma unroll
    for (int c = 0; c < EMB_DIM; ++c) q[c] = x[c] * x[c];
    float r0 = q[0], r1 = q[1], r2 = q[2], r3 = q[3];
    float r4 = q[4], r5 = q[5], r6 = q[6], r7 = q[7];
    #pragma unroll
    for (int g = 1; g < 8; ++g) {
        r0 += q[8 * g + 0]; r1 += q[8 * g + 1];
        r2 += q[8 * g + 2]; r3 += q[8 * g + 3];
        r4 += q[8 * g + 4]; r5 += q[8 * g + 5];
        r6 += q[8 * g + 6]; r7 += q[8 * g + 7];
    }
    return ((r0 + r1) + (r2 + r3)) + ((r4 + r5) + (r6 + r7));
}

// launch_bounds(256, 2): 2 waves/SIMD target -> up to 256 VGPRs/wave.
// z[64] must stay in registers; grid itself only provides 2 waves/SIMD.
__global__ __launch_bounds__(256, 2) void vq_nn(const float* __restrict__ z_e,
                                                const float* __restrict__ emb,
                                                float* __restrict__ zq_out,
                                                float* __restrict__ enc_out,
                                                float* __restrict__ loss_acc) {
    #pragma clang fp contract(off)
    __shared__ float s_e2[NUM_EMB];
    int tid = threadIdx.x;
    for (int k = tid; k < NUM_EMB; k += 256)
        s_e2[k] = np_sumsq64(emb + k * EMB_DIM);
    __syncthreads();

    int p  = blockIdx.x * 256 + tid;       // grid covers NPIX exactly
    int b  = p >> 12;
    int hw = p & 4095;

    const float* zp = z_e + (size_t)b * (EMB_DIM * 4096) + hw;
    float z[EMB_DIM];
    #pragma unroll
    for (int c = 0; c < EMB_DIM; ++c) z[c] = zp[(size_t)c * 4096];

    // zz exactly as np.sum(z**2, axis=-1) computes it (pairwise, n=64)
    float zz = np_sumsq64(z);

    // dist[k] = fl( fl(zz + e2[k]) - fl(2 * dot[k]) ), dot = the SAME
    // sequential fmaf chain (c ascending) as the round-5 passing kernel.
    // float4 loads of the emb row; unroll 2 = two independent FMA chains.
    float b1 = 3.4e38f;
    int   i1 = 0;
    #pragma unroll 2
    for (int k = 0; k < NUM_EMB; ++k) {
        const float* ek = emb + k * EMB_DIM;
        float acc = 0.f;
        #pragma unroll
        for (int c = 0; c < EMB_DIM; c += 4) {
            float4 e4 = *reinterpret_cast<const float4*>(ek + c);
            acc = fmaf(e4.x, z[c + 0], acc);
            acc = fmaf(e4.y, z[c + 1], acc);
            acc = fmaf(e4.z, z[c + 2], acc);
            acc = fmaf(e4.w, z[c + 3], acc);
        }
        float sc = (zz + s_e2[k]) - 2.0f * acc;
        bool lt = sc < b1;
        b1 = lt ? sc : b1;
        i1 = lt ? k  : i1;
    }

    // Gather winning code, write z_q (f32, channel-strided) + loss partial.
    const float* eq = emb + i1 * EMB_DIM;
    float* op = zq_out + (size_t)b * (EMB_DIM * 4096) + hw;
    float ls = 0.f;
    #pragma unroll
    for (int c = 0; c < EMB_DIM; ++c) {
        float q = eq[c];
        float d = q - z[c];
        ls = fmaf(d, d, ls);
        op[(size_t)c * 4096] = q;
    }

    enc_out[p] = (float)i1;

    // wave-level reduce, one atomic per wave into the loss slot
    #pragma unroll
    for (int off = 32; off > 0; off >>= 1) ls += __shfl_down(ls, off, 64);
    if ((tid & 63) == 0) atomicAdd(loss_acc, ls);
}

__global__ void vq_final(float* __restrict__ loss_out) {
    loss_out[0] = loss_out[0] * (1.25f / (float)ZQ_ELEMS);
}

extern "C" void kernel_launch(void* const* d_in, const int* in_sizes, int n_in,
                              void* d_out, int out_size, void* d_ws, size_t ws_size,
                              hipStream_t stream) {
    const float* z_e = (const float*)d_in[0];
    const float* emb = (const float*)d_in[1];
    float* out = (float*)d_out;

    float* loss_out = out + ZQ_ELEMS;        // f32 slot 8388608
    float* enc_out  = out + ZQ_ELEMS + 1;    // f32 slots 8388609..8519680

    vq_zero<<<1, 1, 0, stream>>>(loss_out);
    vq_nn<<<NPIX / 256, 256, 0, stream>>>(z_e, emb, out, enc_out, loss_out);
    vq_final<<<1, 1, 0, stream>>>(loss_out);
}

// Round 7
// 174.701 us; speedup vs baseline: 2.3805x; 2.3805x over previous
//
#include <hip/hip_runtime.h>
#include <hip/hip_bf16.h>

#define NUM_EMB 1024
#define EMB_DIM 64
#define NPIX    131072                 // 32*64*64 pixels
#define ZQ_ELEMS 8388608               // NPIX * EMB_DIM
#define KDEPTH  12

// d_out FLOAT32: [ z_q (8388608, b-c-h-w) | loss (1) | enc (131072) ]
// d_ws: [ E' = bf16(-2*emb) [1024][64] : 131072 B | e2 f32 [1024] : 4096 B ]

typedef __attribute__((ext_vector_type(8))) short short8_t;  // bf16x8 frag
typedef __attribute__((ext_vector_type(4))) float f32x4;     // mfma acc
typedef __attribute__((ext_vector_type(4))) unsigned int u32x4;

__global__ void vq_zero(float* __restrict__ loss_out) { loss_out[0] = 0.f; }

// numpy pairwise-sum (n=64, 8-accumulator) of x[j]^2 — token-identical to the
// round-5/6 PASSING kernel (bit-matches np.sum(x**2, axis=-1)).
__device__ __forceinline__ float np_sumsq64(const float* __restrict__ x) {
    float q[EMB_DIM];
    #pragma unroll
    for (int c = 0; c < EMB_DIM; ++c) q[c] = x[c] * x[c];
    float r0 = q[0], r1 = q[1], r2 = q[2], r3 = q[3];
    float r4 = q[4], r5 = q[5], r6 = q[6], r7 = q[7];
    #pragma unroll
    for (int g = 1; g < 8; ++g) {
        r0 += q[8 * g + 0]; r1 += q[8 * g + 1];
        r2 += q[8 * g + 2]; r3 += q[8 * g + 3];
        r4 += q[8 * g + 4]; r5 += q[8 * g + 5];
        r6 += q[8 * g + 6]; r7 += q[8 * g + 7];
    }
    return ((r0 + r1) + (r2 + r3)) + ((r4 + r5) + (r6 + r7));
}

// Prep: E' = bf16(-2*emb) (exact *2 scale) and np-exact e2 into d_ws.
__global__ __launch_bounds__(256) void vq_prep(const float* __restrict__ emb,
                                               short* __restrict__ wsE,
                                               float* __restrict__ wsE2) {
    #pragma clang fp contract(off)
    int k = blockIdx.x * 256 + threadIdx.x;       // grid = 4 x 256
    const float* ek = emb + k * EMB_DIM;
    wsE2[k] = np_sumsq64(ek);
    #pragma unroll
    for (int c = 0; c < EMB_DIM; ++c) {
        __hip_bfloat16 h = __float2bfloat16(-2.0f * ek[c]);
        unsigned short u; __builtin_memcpy(&u, &h, 2);
        wsE[k * EMB_DIM + c] = (short)u;
    }
}

// ---------------------------------------------------------------------------
// Main kernel: 256 threads = 4 waves, 256 pixels/block (lane<->pixel, bp=tid).
// Pass A: bf16 MFMA screen -> per-pixel min. Pass B: recompute, collect all k
// within error band into per-pixel LDS buffer. Eval: exact np-f32 formula
// (round-5-proven token sequence) on candidates; lexicographic (val,k) min.
// ---------------------------------------------------------------------------
__global__ __launch_bounds__(256, 2) void vq_mfma(const float* __restrict__ z_e,
                                                  const float* __restrict__ emb,
                                                  const short* __restrict__ wsE,
                                                  const float* __restrict__ wsE2,
                                                  float* __restrict__ zq_out,
                                                  float* __restrict__ enc_out,
                                                  float* __restrict__ loss_acc) {
    #pragma clang fp contract(off)
    __shared__ short sE[256 * EMB_DIM];          // 32 KB: quarter of E', swizzled
    __shared__ short sZ[256 * EMB_DIM];          // 32 KB: z bf16 tile, swizzled
    __shared__ float sE2[NUM_EMB];               // 4 KB
    __shared__ unsigned short sKbuf[256][KDEPTH];// 6 KB
    __shared__ int   sKcnt[256];                 // 1 KB
    __shared__ float sBp[256];                   // 1 KB

    const int tid  = threadIdx.x;
    const int w    = tid >> 6;
    const int lane = tid & 63;
    const int bp   = tid;                        // block-pixel id == lane of wave w
    const int p0   = blockIdx.x * 256;
    const int b    = p0 >> 12;                   // uniform (256 | 4096)
    const int hw0  = p0 & 4095;

    for (int i = tid; i < NUM_EMB; i += 256) sE2[i] = wsE2[i];
    sKcnt[tid] = 0;

    // --- load my pixel's z row: np-exact zz, sum|z|, bf16 tile (swizzled) ---
    const float* zrow = z_e + (size_t)b * (EMB_DIM * 4096) + hw0 + bp;
    float rr[8] = {0,0,0,0,0,0,0,0};
    float sab = 0.f;
    #pragma unroll
    for (int g = 0; g < 8; ++g) {
        short8_t pk;
        #pragma unroll
        for (int j = 0; j < 8; ++j) {
            float zc = zrow[(size_t)(8 * g + j) * 4096];
            float qq = zc * zc;                  // separate mul (contract off)
            rr[j] += qq;                         // g-ascending per j = np order
            sab += fabsf(zc);
            __hip_bfloat16 h = __float2bfloat16(zc);
            unsigned short u; __builtin_memcpy(&u, &h, 2);
            pk[j] = (short)u;
        }
        int byte = bp * 128 + ((g * 16) ^ ((bp & 7) << 4));
        *(short8_t*)((char*)sZ + byte) = pk;
    }
    const float zz = ((rr[0] + rr[1]) + (rr[2] + rr[3])) + ((rr[4] + rr[5]) + (rr[6] + rr[7]));
    sBp[bp] = 2.0f * (9e-6f * sab + 2e-5f);      // candidate band (error bound)
    __syncthreads();

    // --- B fragments (z bf16), 4 pixel-groups x 2 K-halves, built once ---
    short8_t bfrag[4][2];
    #pragma unroll
    for (int pg = 0; pg < 4; ++pg)
        #pragma unroll
        for (int h = 0; h < 2; ++h) {
            int bpr  = w * 64 + pg * 16 + (lane & 15);
            int gr   = 4 * h + (lane >> 4);
            int byte = bpr * 128 + ((gr * 16) ^ ((bpr & 7) << 4));
            bfrag[pg][h] = *(const short8_t*)((const char*)sZ + byte);
        }

    float m[4] = {1e30f, 1e30f, 1e30f, 1e30f};

    // ============ PASS A: min scan, and PASS B: collect band ============
    #pragma unroll 1
    for (int pass = 0; pass < 2; ++pass) {
        float thr0 = 0.f, thr1 = 0.f, thr2 = 0.f, thr3 = 0.f;
        if (pass == 1) {
            #pragma unroll
            for (int pg = 0; pg < 4; ++pg) {
                m[pg] = fminf(m[pg], __shfl_xor(m[pg], 16, 64));
                m[pg] = fminf(m[pg], __shfl_xor(m[pg], 32, 64));
            }
            thr0 = m[0] + sBp[w * 64 + 0  + (lane & 15)];
            thr1 = m[1] + sBp[w * 64 + 16 + (lane & 15)];
            thr2 = m[2] + sBp[w * 64 + 32 + (lane & 15)];
            thr3 = m[3] + sBp[w * 64 + 48 + (lane & 15)];
        }
        #pragma unroll 1
        for (int q = 0; q < 4; ++q) {
            __syncthreads();
            for (int gi = tid; gi < 2048; gi += 256) {      // stage 32KB quarter
                u32x4 v = *(const u32x4*)(wsE + q * 16384 + gi * 8);
                int row = gi >> 3, slot = gi & 7;
                int byte = row * 128 + ((slot * 16) ^ ((row & 7) << 4));
                *(u32x4*)((char*)sE + byte) = v;
            }
            __syncthreads();
            #pragma unroll 1
            for (int ch = 0; ch < 16; ++ch) {
                int crow = ch * 16 + (lane & 15);
                int a0b = crow * 128 + ((16 * (lane >> 4)) ^ ((crow & 7) << 4));
                int a1b = crow * 128 + ((64 + 16 * (lane >> 4)) ^ ((crow & 7) << 4));
                short8_t A0 = *(const short8_t*)((const char*)sE + a0b);
                short8_t A1 = *(const short8_t*)((const char*)sE + a1b);
                int kbase = q * 256 + ch * 16 + 4 * (lane >> 4);
                f32x4 e2v = *(const f32x4*)(&sE2[kbase]);
                #pragma unroll
                for (int pg = 0; pg < 4; ++pg) {
                    f32x4 acc = {0.f, 0.f, 0.f, 0.f};
                    acc = __builtin_amdgcn_mfma_f32_16x16x32_bf16(A0, bfrag[pg][0], acc, 0, 0, 0);
                    acc = __builtin_amdgcn_mfma_f32_16x16x32_bf16(A1, bfrag[pg][1], acc, 0, 0, 0);
                    float thr = (pg == 0) ? thr0 : (pg == 1) ? thr1 : (pg == 2) ? thr2 : thr3;
                    #pragma unroll
                    for (int j = 0; j < 4; ++j) {
                        float s = acc[j] + e2v[j];
                        if (pass == 0) {
                            m[pg] = fminf(m[pg], s);
                        } else if (s <= thr) {
                            int pix  = w * 64 + pg * 16 + (lane & 15);
                            int slot = atomicAdd(&sKcnt[pix], 1);
                            if (slot < KDEPTH) sKbuf[pix][slot] = (unsigned short)(kbase + j);
                        }
                    }
                }
            }
        }
    }
    __syncthreads();

    // ============ EXACT EVAL: lane <-> pixel bp, np-f32 formula ============
    int rawcnt = sKcnt[bp];
    int cnt = rawcnt > KDEPTH ? KDEPTH : rawcnt;
    int wmax = cnt;
    #pragma unroll
    for (int off = 32; off > 0; off >>= 1) {
        int o = __shfl_xor(wmax, off, 64);
        wmax = o > wmax ? o : wmax;
    }
    float bestv = 1e30f; int bestk = NUM_EMB;
    for (int s0 = 0; s0 < wmax; s0 += 4) {
        int k0 = (s0 + 0 < cnt) ? (int)sKbuf[bp][s0 + 0] : 0;
        int k1 = (s0 + 1 < cnt) ? (int)sKbuf[bp][s0 + 1] : 0;
        int k2 = (s0 + 2 < cnt) ? (int)sKbuf[bp][s0 + 2] : 0;
        int k3 = (s0 + 3 < cnt) ? (int)sKbuf[bp][s0 + 3] : 0;
        const float *e0 = emb + k0 * EMB_DIM, *e1 = emb + k1 * EMB_DIM;
        const float *e2p = emb + k2 * EMB_DIM, *e3 = emb + k3 * EMB_DIM;
        float a0 = 0.f, a1 = 0.f, a2 = 0.f, a3 = 0.f;
        #pragma unroll 8
        for (int c = 0; c < EMB_DIM; ++c) {      // sequential fmaf chains (np/BLAS order)
            float zc = zrow[(size_t)c * 4096];   // coalesced across lanes, L2-hot
            a0 = fmaf(e0[c], zc, a0);
            a1 = fmaf(e1[c], zc, a1);
            a2 = fmaf(e2p[c], zc, a2);
            a3 = fmaf(e3[c], zc, a3);
        }
        float v0 = (zz + sE2[k0]) - 2.0f * a0;   // exact np token sequence
        float v1 = (zz + sE2[k1]) - 2.0f * a1;
        float v2 = (zz + sE2[k2]) - 2.0f * a2;
        float v3 = (zz + sE2[k3]) - 2.0f * a3;
        if (s0 + 0 < cnt && (v0 < bestv || (v0 == bestv && k0 < bestk))) { bestv = v0; bestk = k0; }
        if (s0 + 1 < cnt && (v1 < bestv || (v1 == bestv && k1 < bestk))) { bestv = v1; bestk = k1; }
        if (s0 + 2 < cnt && (v2 < bestv || (v2 == bestv && k2 < bestk))) { bestv = v2; bestk = k2; }
        if (s0 + 3 < cnt && (v3 < bestv || (v3 == bestv && k3 < bestk))) { bestv = v3; bestk = k3; }
    }
    if (rawcnt > KDEPTH) {                        // overflow safety net (~never)
        bestv = 1e30f; bestk = 0;
        for (int k = 0; k < NUM_EMB; ++k) {
            float acc = 0.f;
            #pragma unroll 8
            for (int c = 0; c < EMB_DIM; ++c)
                acc = fmaf(emb[k * EMB_DIM + c], zrow[(size_t)c * 4096], acc);
            float val = (zz + sE2[k]) - 2.0f * acc;
            if (val < bestv) { bestv = val; bestk = k; }
        }
    }

    enc_out[p0 + bp] = (float)bestk;

    // ============ epilogue: z_q + loss ============
    const float* eq = emb + bestk * EMB_DIM;
    float* op = zq_out + (size_t)b * (EMB_DIM * 4096) + hw0 + bp;
    float ls = 0.f;
    #pragma unroll 8
    for (int c = 0; c < EMB_DIM; ++c) {
        float qv = eq[c];
        float zc = zrow[(size_t)c * 4096];
        float d = qv - zc;
        ls = fmaf(d, d, ls);
        op[(size_t)c * 4096] = qv;               // coalesced across lanes
    }
    #pragma unroll
    for (int off = 32; off > 0; off >>= 1) ls += __shfl_down(ls, off, 64);
    if (lane == 0) atomicAdd(loss_acc, ls);
}

__global__ void vq_final(float* __restrict__ loss_out) {
    loss_out[0] = loss_out[0] * (1.25f / (float)ZQ_ELEMS);
}

// ---------- fallback (round-6 passing kernel) if d_ws is too small ----------
__global__ __launch_bounds__(256) void vq_nn_fb(const float* __restrict__ z_e,
                                                const float* __restrict__ emb,
                                                float* __restrict__ zq_out,
                                                float* __restrict__ enc_out,
                                                float* __restrict__ loss_acc) {
    #pragma clang fp contract(off)
    __shared__ float s_e2[NUM_EMB];
    int tid = threadIdx.x;
    for (int k = tid; k < NUM_EMB; k += 256) s_e2[k] = np_sumsq64(emb + k * EMB_DIM);
    __syncthreads();
    int p = blockIdx.x * 256 + tid;
    int b = p >> 12, hw = p & 4095;
    const float* zp = z_e + (size_t)b * (EMB_DIM * 4096) + hw;
    float z[EMB_DIM];
    #pragma unroll
    for (int c = 0; c < EMB_DIM; ++c) z[c] = zp[(size_t)c * 4096];
    float zz = np_sumsq64(z);
    float b1 = 3.4e38f; int i1 = 0;
    #pragma unroll 2
    for (int k = 0; k < NUM_EMB; ++k) {
        const float* ek = emb + k * EMB_DIM;
        float acc = 0.f;
        #pragma unroll
        for (int c = 0; c < EMB_DIM; ++c) acc = fmaf(ek[c], z[c], acc);
        float sc = (zz + s_e2[k]) - 2.0f * acc;
        bool lt = sc < b1; b1 = lt ? sc : b1; i1 = lt ? k : i1;
    }
    const float* eq = emb + i1 * EMB_DIM;
    float* op = zq_out + (size_t)b * (EMB_DIM * 4096) + hw;
    float ls = 0.f;
    #pragma unroll
    for (int c = 0; c < EMB_DIM; ++c) {
        float q = eq[c]; float d = q - z[c];
        ls = fmaf(d, d, ls);
        op[(size_t)c * 4096] = q;
    }
    enc_out[p] = (float)i1;
    #pragma unroll
    for (int off = 32; off > 0; off >>= 1) ls += __shfl_down(ls, off, 64);
    if ((tid & 63) == 0) atomicAdd(loss_acc, ls);
}

extern "C" void kernel_launch(void* const* d_in, const int* in_sizes, int n_in,
                              void* d_out, int out_size, void* d_ws, size_t ws_size,
                              hipStream_t stream) {
    const float* z_e = (const float*)d_in[0];
    const float* emb = (const float*)d_in[1];
    float* out = (float*)d_out;
    float* loss_out = out + ZQ_ELEMS;
    float* enc_out  = out + ZQ_ELEMS + 1;

    vq_zero<<<1, 1, 0, stream>>>(loss_out);
    if (ws_size >= 140 * 1024) {
        short* wsE  = (short*)d_ws;                        // 128 KB
        float* wsE2 = (float*)((char*)d_ws + 131072);      // 4 KB
        vq_prep<<<NUM_EMB / 256, 256, 0, stream>>>(emb, wsE, wsE2);
        vq_mfma<<<NPIX / 256, 256, 0, stream>>>(z_e, emb, wsE, wsE2, out, enc_out, loss_out);
    } else {
        vq_nn_fb<<<NPIX / 256, 256, 0, stream>>>(z_e, emb, out, enc_out, loss_out);
    }
    vq_final<<<1, 1, 0, stream>>>(loss_out);
}

// Round 8
// 159.030 us; speedup vs baseline: 2.6151x; 1.0985x over previous
//
#include <hip/hip_runtime.h>
#include <hip/hip_bf16.h>

#define NUM_EMB 1024
#define EMB_DIM 64
#define NPIX    131072                 // 32*64*64 pixels
#define ZQ_ELEMS 8388608               // NPIX * EMB_DIM
#define KDEPTH  16

// d_out FLOAT32: [ z_q (8388608, b-c-h-w) | loss (1) | enc (131072) ]
// d_ws: [ E'frag: bf16(-2*emb) in MFMA-A fragment order, 128 KB | e2 f32 4 KB ]
// E'frag layout: triple t=(q*16+ch)*64+lane -> 16 shorts at wsE[t*16]:
//   half h, elem j = bf16(-2*emb[code][chan]), code=q*256+ch*16+(lane&15),
//   chan = 32*h + 8*(lane>>4) + j   (== A-operand layout of mfma_16x16x32_bf16)

typedef __attribute__((ext_vector_type(8))) short short8_t;  // bf16x8 frag
typedef __attribute__((ext_vector_type(4))) float f32x4;     // mfma acc

__global__ void vq_zero(float* __restrict__ loss_out) { loss_out[0] = 0.f; }

// numpy pairwise-sum (n=64, 8-accumulator) of x[j]^2 — token-identical to the
// round-5/6/7 PASSING kernels (bit-matches np.sum(x**2, axis=-1)).
__device__ __forceinline__ float np_sumsq64(const float* __restrict__ x) {
    float q[EMB_DIM];
    #pragma unroll
    for (int c = 0; c < EMB_DIM; ++c) q[c] = x[c] * x[c];
    float r0 = q[0], r1 = q[1], r2 = q[2], r3 = q[3];
    float r4 = q[4], r5 = q[5], r6 = q[6], r7 = q[7];
    #pragma unroll
    for (int g = 1; g < 8; ++g) {
        r0 += q[8 * g + 0]; r1 += q[8 * g + 1];
        r2 += q[8 * g + 2]; r3 += q[8 * g + 3];
        r4 += q[8 * g + 4]; r5 += q[8 * g + 5];
        r6 += q[8 * g + 6]; r7 += q[8 * g + 7];
    }
    return ((r0 + r1) + (r2 + r3)) + ((r4 + r5) + (r6 + r7));
}

// Prep: E'frag (swizzled for coalesced A-frag loads) + np-exact e2.
__global__ __launch_bounds__(256) void vq_prep(const float* __restrict__ emb,
                                               short* __restrict__ wsE,
                                               float* __restrict__ wsE2) {
    #pragma clang fp contract(off)
    int t    = blockIdx.x * 256 + threadIdx.x;    // grid = 16 x 256 = 4096
    int l    = t & 63;
    int ch   = (t >> 6) & 15;
    int q    = t >> 10;
    int code = q * 256 + ch * 16 + (l & 15);
    const float* ek = emb + code * EMB_DIM;
    #pragma unroll
    for (int h = 0; h < 2; ++h) {
        short8_t pk;
        #pragma unroll
        for (int j = 0; j < 8; ++j) {
            int chan = 32 * h + 8 * (l >> 4) + j;
            __hip_bfloat16 bv = __float2bfloat16(-2.0f * ek[chan]);
            unsigned short u; __builtin_memcpy(&u, &bv, 2);
            pk[j] = (short)u;
        }
        *(short8_t*)(wsE + t * 16 + h * 8) = pk;
    }
    if (t < NUM_EMB) wsE2[t] = np_sumsq64(emb + t * EMB_DIM);
}

// ---------------------------------------------------------------------------
// Main: 256 threads = 4 waves handle 64 pixels; wave w scans codebook quarter
// w (256 codes). Pass A: bf16-MFMA min (cross-wave LDS reduce). Pass B:
// recompute + collect band candidates. Eval: exact np-f32 formula on
// candidates, lexicographic (val,k) = np argmin semantics.
// ---------------------------------------------------------------------------
__global__ __launch_bounds__(256, 4) void vq_mfma(const float* __restrict__ z_e,
                                                  const float* __restrict__ emb,
                                                  const short* __restrict__ wsE,
                                                  const float* __restrict__ wsE2,
                                                  float* __restrict__ zq_out,
                                                  float* __restrict__ enc_out,
                                                  float* __restrict__ loss_acc) {
    #pragma clang fp contract(off)
    __shared__ short sZ[64 * EMB_DIM];            // 8 KB swizzled bf16 z tile
    __shared__ float sE2[NUM_EMB];                // 4 KB
    __shared__ float sMin[4][64];                 // 1 KB per-wave per-pixel mins
    __shared__ float sBand[64];
    __shared__ float sThr[64];
    __shared__ float sZZ[64];
    __shared__ int   sBest[64];
    __shared__ unsigned short sKbuf[64][KDEPTH];  // 2 KB
    __shared__ int   sKcnt[64];

    const int tid  = threadIdx.x;
    const int w    = tid >> 6;
    const int lane = tid & 63;
    const int p0   = blockIdx.x * 64;
    const int b    = p0 >> 12;                    // uniform (64 | 4096)
    const int hw0  = p0 & 4095;
    const float* base = z_e + (size_t)b * (EMB_DIM * 4096) + hw0;

    for (int i = tid; i < NUM_EMB; i += 256) sE2[i] = wsE2[i];
    if (tid < 64) sKcnt[tid] = 0;

    // --- bf16 tile: thread t -> pixel t&63, channels 16*(t>>6).. (coalesced) ---
    {
        const int bp = tid & 63, cg = tid >> 6;
        const float* zp = base + bp;
        #pragma unroll
        for (int half = 0; half < 2; ++half) {
            short8_t pk;
            #pragma unroll
            for (int j = 0; j < 8; ++j) {
                float zc = zp[(size_t)(16 * cg + 8 * half + j) * 4096];
                __hip_bfloat16 bv = __float2bfloat16(zc);
                unsigned short u; __builtin_memcpy(&u, &bv, 2);
                pk[j] = (short)u;
            }
            int slot = 2 * cg + half;             // 16B slot = channels 8*slot..
            int byte = bp * 128 + ((slot * 16) ^ ((bp & 7) << 4));
            *(short8_t*)((char*)sZ + byte) = pk;
        }
    }
    // --- zz + band (np-exact, one thread per pixel; wave 0 only) ---
    if (tid < 64) {
        const float* zp = base + tid;
        float rr[8] = {0,0,0,0,0,0,0,0};
        float sab = 0.f;
        #pragma unroll
        for (int g = 0; g < 8; ++g)
            #pragma unroll
            for (int j = 0; j < 8; ++j) {
                float zc = zp[(size_t)(8 * g + j) * 4096];
                float qq = zc * zc;               // separate mul (contract off)
                rr[j] += qq;                      // g-ascending per j = np order
                sab += fabsf(zc);
            }
        sZZ[tid]   = ((rr[0] + rr[1]) + (rr[2] + rr[3])) + ((rr[4] + rr[5]) + (rr[6] + rr[7]));
        sBand[tid] = 2.0f * (9e-6f * sab + 2e-5f);
    }
    __syncthreads();

    // --- B fragments (all 64 pixels, 4 pixel-groups x 2 K-halves) ---
    short8_t bfrag[4][2];
    #pragma unroll
    for (int pg = 0; pg < 4; ++pg)
        #pragma unroll
        for (int h = 0; h < 2; ++h) {
            int bpr  = pg * 16 + (lane & 15);
            int gr   = 4 * h + (lane >> 4);
            int byte = bpr * 128 + ((gr * 16) ^ ((bpr & 7) << 4));
            bfrag[pg][h] = *(const short8_t*)((const char*)sZ + byte);
        }

    // A-frag source: this wave's quarter, coalesced 32B/lane per ch step.
    const short8_t* ef = (const short8_t*)wsE + (size_t)w * 2048;

    // ===== PASS A: per-pixel min over this wave's 256 codes =====
    float m[4] = {1e30f, 1e30f, 1e30f, 1e30f};
    #pragma unroll 1
    for (int ch = 0; ch < 16; ++ch) {
        short8_t A0 = ef[(ch * 64 + lane) * 2 + 0];
        short8_t A1 = ef[(ch * 64 + lane) * 2 + 1];
        int kbase = w * 256 + ch * 16 + 4 * (lane >> 4);
        f32x4 e2v = *(const f32x4*)(&sE2[kbase]);
        #pragma unroll
        for (int pg = 0; pg < 4; ++pg) {
            f32x4 acc = {0.f, 0.f, 0.f, 0.f};
            acc = __builtin_amdgcn_mfma_f32_16x16x32_bf16(A0, bfrag[pg][0], acc, 0, 0, 0);
            acc = __builtin_amdgcn_mfma_f32_16x16x32_bf16(A1, bfrag[pg][1], acc, 0, 0, 0);
            #pragma unroll
            for (int j = 0; j < 4; ++j) m[pg] = fminf(m[pg], acc[j] + e2v[j]);
        }
    }
    #pragma unroll
    for (int pg = 0; pg < 4; ++pg) {
        m[pg] = fminf(m[pg], __shfl_xor(m[pg], 16, 64));
        m[pg] = fminf(m[pg], __shfl_xor(m[pg], 32, 64));
    }
    if (lane < 16) {
        #pragma unroll
        for (int pg = 0; pg < 4; ++pg) sMin[w][pg * 16 + lane] = m[pg];
    }
    __syncthreads();
    if (tid < 64) {
        float g = fminf(fminf(sMin[0][tid], sMin[1][tid]), fminf(sMin[2][tid], sMin[3][tid]));
        sThr[tid] = g + sBand[tid];
    }
    __syncthreads();

    // ===== PASS B: recompute (bit-identical), collect band candidates =====
    {
        float thr[4];
        #pragma unroll
        for (int pg = 0; pg < 4; ++pg) thr[pg] = sThr[pg * 16 + (lane & 15)];
        #pragma unroll 1
        for (int ch = 0; ch < 16; ++ch) {
            short8_t A0 = ef[(ch * 64 + lane) * 2 + 0];
            short8_t A1 = ef[(ch * 64 + lane) * 2 + 1];
            int kbase = w * 256 + ch * 16 + 4 * (lane >> 4);
            f32x4 e2v = *(const f32x4*)(&sE2[kbase]);
            #pragma unroll
            for (int pg = 0; pg < 4; ++pg) {
                f32x4 acc = {0.f, 0.f, 0.f, 0.f};
                acc = __builtin_amdgcn_mfma_f32_16x16x32_bf16(A0, bfrag[pg][0], acc, 0, 0, 0);
                acc = __builtin_amdgcn_mfma_f32_16x16x32_bf16(A1, bfrag[pg][1], acc, 0, 0, 0);
                #pragma unroll
                for (int j = 0; j < 4; ++j) {
                    float s = acc[j] + e2v[j];
                    if (s <= thr[pg]) {
                        int pix  = pg * 16 + (lane & 15);
                        int slot = atomicAdd(&sKcnt[pix], 1);
                        if (slot < KDEPTH) sKbuf[pix][slot] = (unsigned short)(kbase + j);
                    }
                }
            }
        }
    }
    __syncthreads();

    // ===== EXACT EVAL: wave w, lanes 0-15 -> pixels w*16..w*16+15 =====
    if (lane < 16) {
        int pix = w * 16 + lane;
        const float* zr = base + pix;
        float zz = sZZ[pix];
        int rawcnt = sKcnt[pix];
        int cnt = rawcnt > KDEPTH ? KDEPTH : rawcnt;
        float bestv = 1e30f; int bestk = NUM_EMB;
        for (int s = 0; s < cnt; ++s) {
            int k = (int)sKbuf[pix][s];
            const float* ek = emb + k * EMB_DIM;
            float acc = 0.f;
            #pragma unroll 8
            for (int c = 0; c < EMB_DIM; ++c)      // sequential fmaf = BLAS order
                acc = fmaf(ek[c], zr[(size_t)c * 4096], acc);
            float v = (zz + sE2[k]) - 2.0f * acc;  // exact np token sequence
            if (v < bestv || (v == bestv && k < bestk)) { bestv = v; bestk = k; }
        }
        if (rawcnt > KDEPTH) {                     // overflow safety net (~never)
            bestv = 1e30f; bestk = 0;
            for (int k = 0; k < NUM_EMB; ++k) {
                const float* ek = emb + k * EMB_DIM;
                float acc = 0.f;
                #pragma unroll 8
                for (int c = 0; c < EMB_DIM; ++c)
                    acc = fmaf(ek[c], zr[(size_t)c * 4096], acc);
                float v = (zz + sE2[k]) - 2.0f * acc;
                if (v < bestv) { bestv = v; bestk = k; }
            }
        }
        sBest[pix] = bestk;
        enc_out[p0 + pix] = (float)bestk;
    }
    __syncthreads();

    // ===== epilogue: z_q + loss (thread -> pixel tid&63, 16 channels) =====
    {
        const int bp = tid & 63, cg = tid >> 6;
        int bestk = sBest[bp];
        const float* eq = emb + bestk * EMB_DIM;
        const float* zp = base + bp;
        float* op = zq_out + (size_t)b * (EMB_DIM * 4096) + hw0 + bp;
        float ls = 0.f;
        #pragma unroll
        for (int j = 0; j < 16; ++j) {
            int c = 16 * cg + j;
            float qv = eq[c];
            float zc = zp[(size_t)c * 4096];
            float d = qv - zc;
            ls = fmaf(d, d, ls);
            op[(size_t)c * 4096] = qv;             // coalesced across lanes
        }
        #pragma unroll
        for (int off = 32; off > 0; off >>= 1) ls += __shfl_down(ls, off, 64);
        if (lane == 0) atomicAdd(loss_acc, ls);
    }
}

__global__ void vq_final(float* __restrict__ loss_out) {
    loss_out[0] = loss_out[0] * (1.25f / (float)ZQ_ELEMS);
}

// ---------- fallback (round-6 passing kernel) if d_ws is too small ----------
__global__ __launch_bounds__(256) void vq_nn_fb(const float* __restrict__ z_e,
                                                const float* __restrict__ emb,
                                                float* __restrict__ zq_out,
                                                float* __restrict__ enc_out,
                                                float* __restrict__ loss_acc) {
    #pragma clang fp contract(off)
    __shared__ float s_e2[NUM_EMB];
    int tid = threadIdx.x;
    for (int k = tid; k < NUM_EMB; k += 256) s_e2[k] = np_sumsq64(emb + k * EMB_DIM);
    __syncthreads();
    int p = blockIdx.x * 256 + tid;
    int b = p >> 12, hw = p & 4095;
    const float* zp = z_e + (size_t)b * (EMB_DIM * 4096) + hw;
    float z[EMB_DIM];
    #pragma unroll
    for (int c = 0; c < EMB_DIM; ++c) z[c] = zp[(size_t)c * 4096];
    float zz = np_sumsq64(z);
    float b1 = 3.4e38f; int i1 = 0;
    #pragma unroll 2
    for (int k = 0; k < NUM_EMB; ++k) {
        const float* ek = emb + k * EMB_DIM;
        float acc = 0.f;
        #pragma unroll
        for (int c = 0; c < EMB_DIM; ++c) acc = fmaf(ek[c], z[c], acc);
        float sc = (zz + s_e2[k]) - 2.0f * acc;
        bool lt = sc < b1; b1 = lt ? sc : b1; i1 = lt ? k : i1;
    }
    const float* eq = emb + i1 * EMB_DIM;
    float* op = zq_out + (size_t)b * (EMB_DIM * 4096) + hw;
    float ls = 0.f;
    #pragma unroll
    for (int c = 0; c < EMB_DIM; ++c) {
        float q = eq[c]; float d = q - z[c];
        ls = fmaf(d, d, ls);
        op[(size_t)c * 4096] = q;
    }
    enc_out[p] = (float)i1;
    #pragma unroll
    for (int off = 32; off > 0; off >>= 1) ls += __shfl_down(ls, off, 64);
    if ((tid & 63) == 0) atomicAdd(loss_acc, ls);
}

extern "C" void kernel_launch(void* const* d_in, const int* in_sizes, int n_in,
                              void* d_out, int out_size, void* d_ws, size_t ws_size,
                              hipStream_t stream) {
    const float* z_e = (const float*)d_in[0];
    const float* emb = (const float*)d_in[1];
    float* out = (float*)d_out;
    float* loss_out = out + ZQ_ELEMS;
    float* enc_out  = out + ZQ_ELEMS + 1;

    vq_zero<<<1, 1, 0, stream>>>(loss_out);
    if (ws_size >= 140 * 1024) {
        short* wsE  = (short*)d_ws;                        // 128 KB frag-order
        float* wsE2 = (float*)((char*)d_ws + 131072);      // 4 KB
        vq_prep<<<16, 256, 0, stream>>>(emb, wsE, wsE2);
        vq_mfma<<<NPIX / 64, 256, 0, stream>>>(z_e, emb, wsE, wsE2, out, enc_out, loss_out);
    } else {
        vq_nn_fb<<<NPIX / 256, 256, 0, stream>>>(z_e, emb, out, enc_out, loss_out);
    }
    vq_final<<<1, 1, 0, stream>>>(loss_out);
}

// Round 9
// 154.816 us; speedup vs baseline: 2.6862x; 1.0272x over previous
//
#include <hip/hip_runtime.h>
#include <hip/hip_bf16.h>

#define NUM_EMB 1024
#define EMB_DIM 64
#define NPIX    131072                 // 32*64*64 pixels
#define ZQ_ELEMS 8388608               // NPIX * EMB_DIM
#define KDEPTH  16
#define ZSTRIDE 65                     // padded f32 LDS stride (conflict-free)

// d_out FLOAT32: [ z_q (8388608, b-c-h-w) | loss (1) | enc (131072) ]
// d_ws: [ E'frag: bf16(-2*emb) in MFMA-A fragment order, 128 KB | e2 f32 4 KB ]

typedef __attribute__((ext_vector_type(8))) short short8_t;  // bf16x8 frag
typedef __attribute__((ext_vector_type(4))) float f32x4;     // mfma acc

__global__ void vq_zero(float* __restrict__ loss_out) { loss_out[0] = 0.f; }

// numpy pairwise-sum (n=64, 8-accumulator) of x[j]^2 — token-identical to the
// round-5..8 PASSING kernels (bit-matches np.sum(x**2, axis=-1)).
__device__ __forceinline__ float np_sumsq64(const float* __restrict__ x) {
    float q[EMB_DIM];
    #pragma unroll
    for (int c = 0; c < EMB_DIM; ++c) q[c] = x[c] * x[c];
    float r0 = q[0], r1 = q[1], r2 = q[2], r3 = q[3];
    float r4 = q[4], r5 = q[5], r6 = q[6], r7 = q[7];
    #pragma unroll
    for (int g = 1; g < 8; ++g) {
        r0 += q[8 * g + 0]; r1 += q[8 * g + 1];
        r2 += q[8 * g + 2]; r3 += q[8 * g + 3];
        r4 += q[8 * g + 4]; r5 += q[8 * g + 5];
        r6 += q[8 * g + 6]; r7 += q[8 * g + 7];
    }
    return ((r0 + r1) + (r2 + r3)) + ((r4 + r5) + (r6 + r7));
}

__device__ __forceinline__ unsigned long long packvk(float v, int k) {
    unsigned u = __float_as_uint(v);
    u = (u & 0x80000000u) ? ~u : (u | 0x80000000u);   // monotonic f32 -> u32
    return ((unsigned long long)u << 32) | (unsigned)k;
}

// Prep: E'frag (swizzled for coalesced A-frag loads) + np-exact e2. (unchanged)
__global__ __launch_bounds__(256) void vq_prep(const float* __restrict__ emb,
                                               short* __restrict__ wsE,
                                               float* __restrict__ wsE2) {
    #pragma clang fp contract(off)
    int t    = blockIdx.x * 256 + threadIdx.x;    // grid = 16 x 256 = 4096
    int l    = t & 63;
    int ch   = (t >> 6) & 15;
    int q    = t >> 10;
    int code = q * 256 + ch * 16 + (l & 15);
    const float* ek = emb + code * EMB_DIM;
    #pragma unroll
    for (int h = 0; h < 2; ++h) {
        short8_t pk;
        #pragma unroll
        for (int j = 0; j < 8; ++j) {
            int chan = 32 * h + 8 * (l >> 4) + j;
            __hip_bfloat16 bv = __float2bfloat16(-2.0f * ek[chan]);
            unsigned short u; __builtin_memcpy(&u, &bv, 2);
            pk[j] = (short)u;
        }
        *(short8_t*)(wsE + t * 16 + h * 8) = pk;
    }
    if (t < NUM_EMB) wsE2[t] = np_sumsq64(emb + t * EMB_DIM);
}

// ---------------------------------------------------------------------------
// Main: 256 threads = 4 waves, 64 pixels/block; wave w scans codebook quarter
// w. Screen: bf16 MFMA, C-init = e2. Pass B: recompute + band-collect.
// Eval: exact np-f32 formula, 4 threads/pixel, LDS atomicMin (val,k) pack.
// ---------------------------------------------------------------------------
__global__ __launch_bounds__(256, 4) void vq_mfma(const float* __restrict__ z_e,
                                                  const float* __restrict__ emb,
                                                  const short* __restrict__ wsE,
                                                  const float* __restrict__ wsE2,
                                                  float* __restrict__ zq_out,
                                                  float* __restrict__ enc_out,
                                                  float* __restrict__ loss_acc) {
    #pragma clang fp contract(off)
    __shared__ float sZf[64 * ZSTRIDE];           // 16.6 KB exact f32 z tile
    __shared__ float sE2[NUM_EMB];                // 4 KB
    __shared__ float sMin[4][64];                 // 1 KB
    __shared__ float sBand[64];
    __shared__ float sThr[64];
    __shared__ float sZZ[64];
    __shared__ unsigned long long sBestPack[64];  // (mono(v)<<32)|k
    __shared__ unsigned short sKbuf[64][KDEPTH];  // 2 KB
    __shared__ int   sKcnt[64];

    const int tid  = threadIdx.x;
    const int w    = tid >> 6;
    const int lane = tid & 63;
    const int p0   = blockIdx.x * 64;
    const int b    = p0 >> 12;                    // uniform (64 | 4096)
    const int hw0  = p0 & 4095;
    const float* base = z_e + (size_t)b * (EMB_DIM * 4096) + hw0;

    for (int i = tid; i < NUM_EMB; i += 256) sE2[i] = wsE2[i];
    if (tid < 64) { sKcnt[tid] = 0; sBestPack[tid] = ~0ULL; }

    // --- tile load: thread -> pixel lane, channels 16w..16w+15 (coalesced) ---
    {
        const float* zp = base + lane;
        float v[16];
        #pragma unroll
        for (int j = 0; j < 16; ++j) v[j] = zp[(size_t)(16 * w + j) * 4096];
        #pragma unroll
        for (int j = 0; j < 16; ++j) sZf[lane * ZSTRIDE + 16 * w + j] = v[j];
    }
    __syncthreads();

    // --- wave0: np-exact zz + band from LDS (overlaps waves1-3 pass A) ---
    if (w == 0) {
        const float* zl = &sZf[lane * ZSTRIDE];
        float rr[8] = {0,0,0,0,0,0,0,0};
        float sab = 0.f;
        #pragma unroll
        for (int g = 0; g < 8; ++g)
            #pragma unroll
            for (int j = 0; j < 8; ++j) {
                float zc = zl[8 * g + j];
                float qq = zc * zc;               // separate mul (contract off)
                rr[j] += qq;                      // g-ascending per j = np order
                sab += fabsf(zc);
            }
        sZZ[lane]   = ((rr[0] + rr[1]) + (rr[2] + rr[3])) + ((rr[4] + rr[5]) + (rr[6] + rr[7]));
        sBand[lane] = 2.0f * (9e-6f * sab + 2e-5f);
    }

    // --- B fragments from f32 LDS (RNE cvt, same as before) ---
    short8_t bfrag[4][2];
    #pragma unroll
    for (int pg = 0; pg < 4; ++pg)
        #pragma unroll
        for (int h = 0; h < 2; ++h) {
            int bpr = pg * 16 + (lane & 15);
            int c0  = 32 * h + 8 * (lane >> 4);
            short8_t pk;
            #pragma unroll
            for (int j = 0; j < 8; ++j) {
                __hip_bfloat16 bv = __float2bfloat16(sZf[bpr * ZSTRIDE + c0 + j]);
                unsigned short u; __builtin_memcpy(&u, &bv, 2);
                pk[j] = (short)u;
            }
            bfrag[pg][h] = pk;
        }

    const short8_t* ef = (const short8_t*)wsE + (size_t)w * 2048;

    // ===== PASS A: per-pixel min (C-init = e2; prefetched A-frags) =====
    float m[4] = {1e30f, 1e30f, 1e30f, 1e30f};
    {
        short8_t A0 = ef[lane * 2 + 0];
        short8_t A1 = ef[lane * 2 + 1];
        #pragma unroll 1
        for (int ch = 0; ch < 16; ++ch) {
            int chn = ch < 15 ? ch + 1 : 15;
            short8_t N0 = ef[(chn * 64 + lane) * 2 + 0];
            short8_t N1 = ef[(chn * 64 + lane) * 2 + 1];
            int kbase = w * 256 + ch * 16 + 4 * (lane >> 4);
            f32x4 e2v = *(const f32x4*)(&sE2[kbase]);
            #pragma unroll
            for (int pg = 0; pg < 4; ++pg) {
                f32x4 acc = e2v;
                acc = __builtin_amdgcn_mfma_f32_16x16x32_bf16(A0, bfrag[pg][0], acc, 0, 0, 0);
                acc = __builtin_amdgcn_mfma_f32_16x16x32_bf16(A1, bfrag[pg][1], acc, 0, 0, 0);
                m[pg] = fminf(m[pg], fminf(fminf(acc[0], acc[1]), fminf(acc[2], acc[3])));
            }
            A0 = N0; A1 = N1;
        }
    }
    #pragma unroll
    for (int pg = 0; pg < 4; ++pg) {
        m[pg] = fminf(m[pg], __shfl_xor(m[pg], 16, 64));
        m[pg] = fminf(m[pg], __shfl_xor(m[pg], 32, 64));
    }
    if (lane < 16) {
        #pragma unroll
        for (int pg = 0; pg < 4; ++pg) sMin[w][pg * 16 + lane] = m[pg];
    }
    __syncthreads();
    if (tid < 64)
        sThr[tid] = fminf(fminf(sMin[0][tid], sMin[1][tid]),
                          fminf(sMin[2][tid], sMin[3][tid])) + sBand[tid];
    __syncthreads();

    // ===== PASS B: recompute (bit-identical), collect band candidates =====
    {
        float thr[4];
        #pragma unroll
        for (int pg = 0; pg < 4; ++pg) thr[pg] = sThr[pg * 16 + (lane & 15)];
        short8_t A0 = ef[lane * 2 + 0];
        short8_t A1 = ef[lane * 2 + 1];
        #pragma unroll 1
        for (int ch = 0; ch < 16; ++ch) {
            int chn = ch < 15 ? ch + 1 : 15;
            short8_t N0 = ef[(chn * 64 + lane) * 2 + 0];
            short8_t N1 = ef[(chn * 64 + lane) * 2 + 1];
            int kbase = w * 256 + ch * 16 + 4 * (lane >> 4);
            f32x4 e2v = *(const f32x4*)(&sE2[kbase]);
            #pragma unroll
            for (int pg = 0; pg < 4; ++pg) {
                f32x4 acc = e2v;
                acc = __builtin_amdgcn_mfma_f32_16x16x32_bf16(A0, bfrag[pg][0], acc, 0, 0, 0);
                acc = __builtin_amdgcn_mfma_f32_16x16x32_bf16(A1, bfrag[pg][1], acc, 0, 0, 0);
                #pragma unroll
                for (int j = 0; j < 4; ++j) {
                    if (acc[j] <= thr[pg]) {
                        int pix  = pg * 16 + (lane & 15);
                        int slot = atomicAdd(&sKcnt[pix], 1);
                        if (slot < KDEPTH) sKbuf[pix][slot] = (unsigned short)(kbase + j);
                    }
                }
            }
            A0 = N0; A1 = N1;
        }
    }
    __syncthreads();

    // ===== EXACT EVAL: 4 threads/pixel (wave w = slot offset w) =====
    {
        const int px = lane;                       // pixel
        const float* zl = &sZf[px * ZSTRIDE];
        float zzv = sZZ[px];
        int rawcnt = sKcnt[px];
        if (rawcnt <= KDEPTH) {
            for (int s = w; s < rawcnt; s += 4) {
                int k = (int)sKbuf[px][s];
                const float* ek = emb + k * EMB_DIM;
                float acc = 0.f;
                #pragma unroll 8
                for (int c = 0; c < EMB_DIM; ++c)   // sequential fmaf = BLAS order
                    acc = fmaf(ek[c], zl[c], acc);
                float v = (zzv + sE2[k]) - 2.0f * acc;  // exact np token sequence
                atomicMin(&sBestPack[px], packvk(v, k));
            }
        } else {                                   // overflow safety net (~never)
            for (int k = w; k < NUM_EMB; k += 4) {
                const float* ek = emb + k * EMB_DIM;
                float acc = 0.f;
                #pragma unroll 8
                for (int c = 0; c < EMB_DIM; ++c)
                    acc = fmaf(ek[c], zl[c], acc);
                float v = (zzv + sE2[k]) - 2.0f * acc;
                atomicMin(&sBestPack[px], packvk(v, k));
            }
        }
    }
    __syncthreads();

    // ===== enc + epilogue (z from LDS; coalesced z_q stores) =====
    if (tid < 64)
        enc_out[p0 + tid] = (float)(unsigned)(sBestPack[tid] & 0xFFFFFFFFull);
    {
        const int px = lane;
        int bestk = (int)(sBestPack[px] & 0xFFFFFFFFull);
        const float* eq = emb + bestk * EMB_DIM;
        const float* zl = &sZf[px * ZSTRIDE];
        float* op = zq_out + (size_t)b * (EMB_DIM * 4096) + hw0 + px;
        float ls = 0.f;
        #pragma unroll
        for (int j = 0; j < 16; ++j) {
            int c = 16 * w + j;
            float qv = eq[c];
            float d = qv - zl[c];
            ls = fmaf(d, d, ls);
            op[(size_t)c * 4096] = qv;
        }
        #pragma unroll
        for (int off = 32; off > 0; off >>= 1) ls += __shfl_down(ls, off, 64);
        if (lane == 0) atomicAdd(loss_acc, ls);
    }
}

__global__ void vq_final(float* __restrict__ loss_out) {
    loss_out[0] = loss_out[0] * (1.25f / (float)ZQ_ELEMS);
}

// ---------- fallback (round-6 passing kernel) if d_ws is too small ----------
__global__ __launch_bounds__(256) void vq_nn_fb(const float* __restrict__ z_e,
                                                const float* __restrict__ emb,
                                                float* __restrict__ zq_out,
                                                float* __restrict__ enc_out,
                                                float* __restrict__ loss_acc) {
    #pragma clang fp contract(off)
    __shared__ float s_e2[NUM_EMB];
    int tid = threadIdx.x;
    for (int k = tid; k < NUM_EMB; k += 256) s_e2[k] = np_sumsq64(emb + k * EMB_DIM);
    __syncthreads();
    int p = blockIdx.x * 256 + tid;
    int b = p >> 12, hw = p & 4095;
    const float* zp = z_e + (size_t)b * (EMB_DIM * 4096) + hw;
    float z[EMB_DIM];
    #pragma unroll
    for (int c = 0; c < EMB_DIM; ++c) z[c] = zp[(size_t)c * 4096];
    float zz = np_sumsq64(z);
    float b1 = 3.4e38f; int i1 = 0;
    #pragma unroll 2
    for (int k = 0; k < NUM_EMB; ++k) {
        const float* ek = emb + k * EMB_DIM;
        float acc = 0.f;
        #pragma unroll
        for (int c = 0; c < EMB_DIM; ++c) acc = fmaf(ek[c], z[c], acc);
        float sc = (zz + s_e2[k]) - 2.0f * acc;
        bool lt = sc < b1; b1 = lt ? sc : b1; i1 = lt ? k : i1;
    }
    const float* eq = emb + i1 * EMB_DIM;
    float* op = zq_out + (size_t)b * (EMB_DIM * 4096) + hw;
    float ls = 0.f;
    #pragma unroll
    for (int c = 0; c < EMB_DIM; ++c) {
        float q = eq[c]; float d = q - z[c];
        ls = fmaf(d, d, ls);
        op[(size_t)c * 4096] = q;
    }
    enc_out[p] = (float)i1;
    #pragma unroll
    for (int off = 32; off > 0; off >>= 1) ls += __shfl_down(ls, off, 64);
    if ((tid & 63) == 0) atomicAdd(loss_acc, ls);
}

extern "C" void kernel_launch(void* const* d_in, const int* in_sizes, int n_in,
                              void* d_out, int out_size, void* d_ws, size_t ws_size,
                              hipStream_t stream) {
    const float* z_e = (const float*)d_in[0];
    const float* emb = (const float*)d_in[1];
    float* out = (float*)d_out;
    float* loss_out = out + ZQ_ELEMS;
    float* enc_out  = out + ZQ_ELEMS + 1;

    vq_zero<<<1, 1, 0, stream>>>(loss_out);
    if (ws_size >= 140 * 1024) {
        short* wsE  = (short*)d_ws;                        // 128 KB frag-order
        float* wsE2 = (float*)((char*)d_ws + 131072);      // 4 KB
        vq_prep<<<16, 256, 0, stream>>>(emb, wsE, wsE2);
        vq_mfma<<<NPIX / 64, 256, 0, stream>>>(z_e, emb, wsE, wsE2, out, enc_out, loss_out);
    } else {
        vq_nn_fb<<<NPIX / 256, 256, 0, stream>>>(z_e, emb, out, enc_out, loss_out);
    }
    vq_final<<<1, 1, 0, stream>>>(loss_out);
}

// Round 10
// 102.347 us; speedup vs baseline: 4.0634x; 1.5127x over previous
//
#include <hip/hip_runtime.h>
#include <hip/hip_bf16.h>

#define NUM_EMB 1024
#define EMB_DIM 64
#define NPIX    131072                 // 32*64*64 pixels
#define ZQ_ELEMS 8388608               // NPIX * EMB_DIM
#define KDEPTH  16
#define ZSTRIDE 65                     // padded f32 LDS stride (conflict-free)
#define NACC    64                     // spread loss accumulators

// d_out FLOAT32: [ z_q (8388608, b-c-h-w) | loss (1) | enc (131072) ]
// d_ws: [ E'frag 128KB | e2 f32 4KB | lossAcc f32[64] @135168 ]

typedef __attribute__((ext_vector_type(8))) short short8_t;  // bf16x8 frag
typedef __attribute__((ext_vector_type(4))) float f32x4;     // mfma acc

__global__ void vq_zero_ws(float* __restrict__ loss_out, float* __restrict__ wsAcc) {
    if (threadIdx.x == 0) loss_out[0] = 0.f;
    wsAcc[threadIdx.x] = 0.f;          // 64 threads
}

// numpy pairwise-sum (n=64, 8-accumulator) of x[j]^2 — token-identical to the
// round-5..9 PASSING kernels (bit-matches np.sum(x**2, axis=-1)).
__device__ __forceinline__ float np_sumsq64(const float* __restrict__ x) {
    float q[EMB_DIM];
    #pragma unroll
    for (int c = 0; c < EMB_DIM; ++c) q[c] = x[c] * x[c];
    float r0 = q[0], r1 = q[1], r2 = q[2], r3 = q[3];
    float r4 = q[4], r5 = q[5], r6 = q[6], r7 = q[7];
    #pragma unroll
    for (int g = 1; g < 8; ++g) {
        r0 += q[8 * g + 0]; r1 += q[8 * g + 1];
        r2 += q[8 * g + 2]; r3 += q[8 * g + 3];
        r4 += q[8 * g + 4]; r5 += q[8 * g + 5];
        r6 += q[8 * g + 6]; r7 += q[8 * g + 7];
    }
    return ((r0 + r1) + (r2 + r3)) + ((r4 + r5) + (r6 + r7));
}

__device__ __forceinline__ unsigned long long packvk(float v, int k) {
    unsigned u = __float_as_uint(v);
    u = (u & 0x80000000u) ? ~u : (u | 0x80000000u);   // monotonic f32 -> u32
    return ((unsigned long long)u << 32) | (unsigned)k;
}

// Prep: E'frag (swizzled for coalesced A-frag loads) + np-exact e2. (unchanged)
__global__ __launch_bounds__(256) void vq_prep(const float* __restrict__ emb,
                                               short* __restrict__ wsE,
                                               float* __restrict__ wsE2) {
    #pragma clang fp contract(off)
    int t    = blockIdx.x * 256 + threadIdx.x;    // grid = 16 x 256 = 4096
    int l    = t & 63;
    int ch   = (t >> 6) & 15;
    int q    = t >> 10;
    int code = q * 256 + ch * 16 + (l & 15);
    const float* ek = emb + code * EMB_DIM;
    #pragma unroll
    for (int h = 0; h < 2; ++h) {
        short8_t pk;
        #pragma unroll
        for (int j = 0; j < 8; ++j) {
            int chan = 32 * h + 8 * (l >> 4) + j;
            __hip_bfloat16 bv = __float2bfloat16(-2.0f * ek[chan]);
            unsigned short u; __builtin_memcpy(&u, &bv, 2);
            pk[j] = (short)u;
        }
        *(short8_t*)(wsE + t * 16 + h * 8) = pk;
    }
    if (t < NUM_EMB) wsE2[t] = np_sumsq64(emb + t * EMB_DIM);
}

// ---------------------------------------------------------------------------
// Main: 256 threads = 4 waves, 64 pixels/block; wave w scans codebook quarter
// w. Screen: bf16 MFMA, C-init = e2, B-frags PINNED in VGPRs. Pass B:
// recompute + band-collect. Eval: exact np-f32, 4 threads/pixel.
// Loss: per-wave partial -> spread ws accumulators (no same-address storm).
// ---------------------------------------------------------------------------
__global__ __launch_bounds__(256, 4) void vq_mfma(const float* __restrict__ z_e,
                                                  const float* __restrict__ emb,
                                                  const short* __restrict__ wsE,
                                                  const float* __restrict__ wsE2,
                                                  float* __restrict__ zq_out,
                                                  float* __restrict__ enc_out,
                                                  float* __restrict__ wsAcc) {
    #pragma clang fp contract(off)
    __shared__ float sZf[64 * ZSTRIDE];           // 16.6 KB exact f32 z tile
    __shared__ float sE2[NUM_EMB];                // 4 KB
    __shared__ float sMin[4][64];                 // 1 KB
    __shared__ float sBand[64];
    __shared__ float sThr[64];
    __shared__ float sZZ[64];
    __shared__ unsigned long long sBestPack[64];  // (mono(v)<<32)|k
    __shared__ unsigned short sKbuf[64][KDEPTH];  // 2 KB
    __shared__ int   sKcnt[64];

    const int tid  = threadIdx.x;
    const int w    = tid >> 6;
    const int lane = tid & 63;
    const int p0   = blockIdx.x * 64;
    const int b    = p0 >> 12;                    // uniform (64 | 4096)
    const int hw0  = p0 & 4095;
    const float* base = z_e + (size_t)b * (EMB_DIM * 4096) + hw0;

    for (int i = tid; i < NUM_EMB; i += 256) sE2[i] = wsE2[i];
    if (tid < 64) { sKcnt[tid] = 0; sBestPack[tid] = ~0ULL; }

    // --- tile load: thread -> pixel lane, channels 16w..16w+15 (coalesced) ---
    {
        const float* zp = base + lane;
        float v[16];
        #pragma unroll
        for (int j = 0; j < 16; ++j) v[j] = zp[(size_t)(16 * w + j) * 4096];
        #pragma unroll
        for (int j = 0; j < 16; ++j) sZf[lane * ZSTRIDE + 16 * w + j] = v[j];
    }
    __syncthreads();

    // --- wave0: np-exact zz + band from LDS (overlaps other waves) ---
    if (w == 0) {
        const float* zl = &sZf[lane * ZSTRIDE];
        float rr[8] = {0,0,0,0,0,0,0,0};
        float sab = 0.f;
        #pragma unroll
        for (int g = 0; g < 8; ++g)
            #pragma unroll
            for (int j = 0; j < 8; ++j) {
                float zc = zl[8 * g + j];
                float qq = zc * zc;               // separate mul (contract off)
                rr[j] += qq;                      // g-ascending per j = np order
                sab += fabsf(zc);
            }
        sZZ[lane]   = ((rr[0] + rr[1]) + (rr[2] + rr[3])) + ((rr[4] + rr[5]) + (rr[6] + rr[7]));
        sBand[lane] = 2.0f * (9e-6f * sab + 2e-5f);
    }

    // --- B fragments from f32 LDS, then PIN in VGPRs (no LDS remat) ---
    short8_t bfrag[4][2];
    #pragma unroll
    for (int pg = 0; pg < 4; ++pg)
        #pragma unroll
        for (int h = 0; h < 2; ++h) {
            int bpr = pg * 16 + (lane & 15);
            int c0  = 32 * h + 8 * (lane >> 4);
            short8_t pk;
            #pragma unroll
            for (int j = 0; j < 8; ++j) {
                __hip_bfloat16 bv = __float2bfloat16(sZf[bpr * ZSTRIDE + c0 + j]);
                unsigned short u; __builtin_memcpy(&u, &bv, 2);
                pk[j] = (short)u;
            }
            asm volatile("" : "+v"(pk));          // force materialization
            bfrag[pg][h] = pk;
        }

    const short8_t* ef = (const short8_t*)wsE + (size_t)w * 2048;

    // ===== PASS A: per-pixel min (C-init = e2; prefetched A-frags) =====
    float m[4] = {1e30f, 1e30f, 1e30f, 1e30f};
    {
        short8_t A0 = ef[lane * 2 + 0];
        short8_t A1 = ef[lane * 2 + 1];
        #pragma unroll 1
        for (int ch = 0; ch < 16; ++ch) {
            int chn = ch < 15 ? ch + 1 : 15;
            short8_t N0 = ef[(chn * 64 + lane) * 2 + 0];
            short8_t N1 = ef[(chn * 64 + lane) * 2 + 1];
            int kbase = w * 256 + ch * 16 + 4 * (lane >> 4);
            f32x4 e2v = *(const f32x4*)(&sE2[kbase]);
            #pragma unroll
            for (int pg = 0; pg < 4; ++pg) {
                f32x4 acc = e2v;
                acc = __builtin_amdgcn_mfma_f32_16x16x32_bf16(A0, bfrag[pg][0], acc, 0, 0, 0);
                acc = __builtin_amdgcn_mfma_f32_16x16x32_bf16(A1, bfrag[pg][1], acc, 0, 0, 0);
                m[pg] = fminf(m[pg], fminf(fminf(acc[0], acc[1]), fminf(acc[2], acc[3])));
            }
            A0 = N0; A1 = N1;
        }
    }
    #pragma unroll
    for (int pg = 0; pg < 4; ++pg) {
        m[pg] = fminf(m[pg], __shfl_xor(m[pg], 16, 64));
        m[pg] = fminf(m[pg], __shfl_xor(m[pg], 32, 64));
    }
    if (lane < 16) {
        #pragma unroll
        for (int pg = 0; pg < 4; ++pg) sMin[w][pg * 16 + lane] = m[pg];
    }
    __syncthreads();
    if (tid < 64)
        sThr[tid] = fminf(fminf(sMin[0][tid], sMin[1][tid]),
                          fminf(sMin[2][tid], sMin[3][tid])) + sBand[tid];
    __syncthreads();

    // ===== PASS B: recompute (bit-identical), collect band candidates =====
    {
        float thr[4];
        #pragma unroll
        for (int pg = 0; pg < 4; ++pg) thr[pg] = sThr[pg * 16 + (lane & 15)];
        short8_t A0 = ef[lane * 2 + 0];
        short8_t A1 = ef[lane * 2 + 1];
        #pragma unroll 1
        for (int ch = 0; ch < 16; ++ch) {
            int chn = ch < 15 ? ch + 1 : 15;
            short8_t N0 = ef[(chn * 64 + lane) * 2 + 0];
            short8_t N1 = ef[(chn * 64 + lane) * 2 + 1];
            int kbase = w * 256 + ch * 16 + 4 * (lane >> 4);
            f32x4 e2v = *(const f32x4*)(&sE2[kbase]);
            #pragma unroll
            for (int pg = 0; pg < 4; ++pg) {
                f32x4 acc = e2v;
                acc = __builtin_amdgcn_mfma_f32_16x16x32_bf16(A0, bfrag[pg][0], acc, 0, 0, 0);
                acc = __builtin_amdgcn_mfma_f32_16x16x32_bf16(A1, bfrag[pg][1], acc, 0, 0, 0);
                #pragma unroll
                for (int j = 0; j < 4; ++j) {
                    if (acc[j] <= thr[pg]) {
                        int pix  = pg * 16 + (lane & 15);
                        int slot = atomicAdd(&sKcnt[pix], 1);
                        if (slot < KDEPTH) sKbuf[pix][slot] = (unsigned short)(kbase + j);
                    }
                }
            }
            A0 = N0; A1 = N1;
        }
    }
    __syncthreads();

    // ===== EXACT EVAL: 4 threads/pixel (wave w = slot offset w) =====
    {
        const int px = lane;
        const float* zl = &sZf[px * ZSTRIDE];
        float zzv = sZZ[px];
        int rawcnt = sKcnt[px];
        if (rawcnt <= KDEPTH) {
            for (int s = w; s < rawcnt; s += 4) {
                int k = (int)sKbuf[px][s];
                const float* ek = emb + k * EMB_DIM;
                float acc = 0.f;
                #pragma unroll 8
                for (int c = 0; c < EMB_DIM; ++c)   // sequential fmaf = BLAS order
                    acc = fmaf(ek[c], zl[c], acc);
                float v = (zzv + sE2[k]) - 2.0f * acc;  // exact np token sequence
                atomicMin(&sBestPack[px], packvk(v, k));
            }
        } else {                                   // overflow safety net (~never)
            for (int k = w; k < NUM_EMB; k += 4) {
                const float* ek = emb + k * EMB_DIM;
                float acc = 0.f;
                #pragma unroll 8
                for (int c = 0; c < EMB_DIM; ++c)
                    acc = fmaf(ek[c], zl[c], acc);
                float v = (zzv + sE2[k]) - 2.0f * acc;
                atomicMin(&sBestPack[px], packvk(v, k));
            }
        }
    }
    __syncthreads();

    // ===== enc + epilogue (z from LDS; coalesced z_q stores) =====
    if (tid < 64)
        enc_out[p0 + tid] = (float)(unsigned)(sBestPack[tid] & 0xFFFFFFFFull);
    {
        const int px = lane;
        int bestk = (int)(sBestPack[px] & 0xFFFFFFFFull);
        const float* eq = emb + bestk * EMB_DIM;
        const float* zl = &sZf[px * ZSTRIDE];
        float* op = zq_out + (size_t)b * (EMB_DIM * 4096) + hw0 + px;
        float ls = 0.f;
        #pragma unroll
        for (int j = 0; j < 16; ++j) {
            int c = 16 * w + j;
            float qv = eq[c];
            float d = qv - zl[c];
            ls = fmaf(d, d, ls);
            op[(size_t)c * 4096] = qv;
        }
        #pragma unroll
        for (int off = 32; off > 0; off >>= 1) ls += __shfl_down(ls, off, 64);
        if (lane == 0) atomicAdd(&wsAcc[blockIdx.x & (NACC - 1)], ls);
    }
}

__global__ void vq_final_ws(const float* __restrict__ wsAcc,
                            float* __restrict__ loss_out) {
    int lane = threadIdx.x;                       // 64 threads
    float v = wsAcc[lane];
    #pragma unroll
    for (int off = 32; off > 0; off >>= 1) v += __shfl_down(v, off, 64);
    if (lane == 0) loss_out[0] = v * (1.25f / (float)ZQ_ELEMS);
}

__global__ void vq_final_direct(float* __restrict__ loss_out) {
    loss_out[0] = loss_out[0] * (1.25f / (float)ZQ_ELEMS);
}

// ---------- fallback (round-6 passing kernel) if d_ws is too small ----------
__global__ __launch_bounds__(256) void vq_nn_fb(const float* __restrict__ z_e,
                                                const float* __restrict__ emb,
                                                float* __restrict__ zq_out,
                                                float* __restrict__ enc_out,
                                                float* __restrict__ loss_acc) {
    #pragma clang fp contract(off)
    __shared__ float s_e2[NUM_EMB];
    int tid = threadIdx.x;
    for (int k = tid; k < NUM_EMB; k += 256) s_e2[k] = np_sumsq64(emb + k * EMB_DIM);
    __syncthreads();
    int p = blockIdx.x * 256 + tid;
    int b = p >> 12, hw = p & 4095;
    const float* zp = z_e + (size_t)b * (EMB_DIM * 4096) + hw;
    float z[EMB_DIM];
    #pragma unroll
    for (int c = 0; c < EMB_DIM; ++c) z[c] = zp[(size_t)c * 4096];
    float zz = np_sumsq64(z);
    float b1 = 3.4e38f; int i1 = 0;
    #pragma unroll 2
    for (int k = 0; k < NUM_EMB; ++k) {
        const float* ek = emb + k * EMB_DIM;
        float acc = 0.f;
        #pragma unroll
        for (int c = 0; c < EMB_DIM; ++c) acc = fmaf(ek[c], z[c], acc);
        float sc = (zz + s_e2[k]) - 2.0f * acc;
        bool lt = sc < b1; b1 = lt ? sc : b1; i1 = lt ? k : i1;
    }
    const float* eq = emb + i1 * EMB_DIM;
    float* op = zq_out + (size_t)b * (EMB_DIM * 4096) + hw;
    float ls = 0.f;
    #pragma unroll
    for (int c = 0; c < EMB_DIM; ++c) {
        float q = eq[c]; float d = q - z[c];
        ls = fmaf(d, d, ls);
        op[(size_t)c * 4096] = q;
    }
    enc_out[p] = (float)i1;
    #pragma unroll
    for (int off = 32; off > 0; off >>= 1) ls += __shfl_down(ls, off, 64);
    if ((tid & 63) == 0) atomicAdd(loss_acc, ls);
}

extern "C" void kernel_launch(void* const* d_in, const int* in_sizes, int n_in,
                              void* d_out, int out_size, void* d_ws, size_t ws_size,
                              hipStream_t stream) {
    const float* z_e = (const float*)d_in[0];
    const float* emb = (const float*)d_in[1];
    float* out = (float*)d_out;
    float* loss_out = out + ZQ_ELEMS;
    float* enc_out  = out + ZQ_ELEMS + 1;

    if (ws_size >= 140 * 1024) {
        short* wsE   = (short*)d_ws;                       // 128 KB frag-order
        float* wsE2  = (float*)((char*)d_ws + 131072);     // 4 KB
        float* wsAcc = (float*)((char*)d_ws + 135168);     // 256 B
        vq_zero_ws<<<1, NACC, 0, stream>>>(loss_out, wsAcc);
        vq_prep<<<16, 256, 0, stream>>>(emb, wsE, wsE2);
        vq_mfma<<<NPIX / 64, 256, 0, stream>>>(z_e, emb, wsE, wsE2, out, enc_out, wsAcc);
        vq_final_ws<<<1, 64, 0, stream>>>(wsAcc, loss_out);
    } else {
        hipMemsetAsync(loss_out, 0, 4, stream);
        vq_nn_fb<<<NPIX / 256, 256, 0, stream>>>(z_e, emb, out, enc_out, loss_out);
        vq_final_direct<<<1, 1, 0, stream>>>(loss_out);
    }
}